// Round 1
// baseline (167.897 us; speedup 1.0000x reference)
//
#include <hip/hip_runtime.h>
#include <math.h>

// NoisyTopkRouter, all-f32.
// x[ntok,384] @ {w_route,w_noise}[8,384]^T -> 16 logits/token,
// noisy = logit + noise*softplus(noise_logit), top-2 of 8, sparse softmax.
// Output: [ntok*8 probs f32 | ntok*2 indices-as-f32].
//
// R7: R5->R6 (2->6 outstanding loads/lane) was a NULL -> not latency-bound.
// Little's law agrees: 16 waves/CU x 6x16B/lane in flight >> the ~9KB/CU
// needed for 6.3 TB/s. dur_us (164) >> any dispatch (<59) -> timed region
// includes the two ~402MB poison fills; our kernel is ~46us = 2.2 TB/s on
// a 16us read floor. New theory: the fills leave all 256MB of L3 dirty;
// our read-allocates force dirty evictions -> HBM serves reads + ~equal
// writebacks with turnaround penalties. Fix: NON-TEMPORAL x/noise loads
// (no L2/L3 allocation -> no forced evictions), nt output stores, drop the
// s=3 dummy re-read (real HBM traffic under nt), and issue the first
// x-superstep before weight staging so its latency hides under the barrier.

constexpr int D = 384;

typedef float vfloat4 __attribute__((ext_vector_type(4)));
typedef float vfloat2 __attribute__((ext_vector_type(2)));

__device__ __forceinline__ float4 ntload4(const float* p) {
    vfloat4 v = __builtin_nontemporal_load((const vfloat4*)p);
    return make_float4(v.x, v.y, v.z, v.w);
}
__device__ __forceinline__ void ntstore4(float* p, float4 v) {
    vfloat4 t = {v.x, v.y, v.z, v.w};
    __builtin_nontemporal_store(t, (vfloat4*)p);
}
__device__ __forceinline__ void ntstore2(float* p, float2 v) {
    vfloat2 t = {v.x, v.y};
    __builtin_nontemporal_store(t, (vfloat2*)p);
}

__device__ __forceinline__ float dpp_xor1(float v) {   // lane ^ 1, quad_perm [1,0,3,2]
    return __int_as_float(__builtin_amdgcn_update_dpp(
        0, __float_as_int(v), 0xB1, 0xF, 0xF, true));
}
__device__ __forceinline__ float dpp_xor2(float v) {   // lane ^ 2, quad_perm [2,3,0,1]
    return __int_as_float(__builtin_amdgcn_update_dpp(
        0, __float_as_int(v), 0x4E, 0xF, 0xF, true));
}
__device__ __forceinline__ float swz_xor4(float v) {   // ds_swizzle BitMode xor 4
    return __int_as_float(__builtin_amdgcn_ds_swizzle(__float_as_int(v), 0x101F));
}

__global__ __launch_bounds__(256, 4) void noisy_topk_router_f32(
    const float* __restrict__ x,        // [ntok,384]
    const float* __restrict__ noise,    // [ntok,8]
    const float* __restrict__ w_route,  // [8,384]
    const float* __restrict__ b_route,  // [8]
    const float* __restrict__ w_noise,  // [8,384]
    const float* __restrict__ b_noise,  // [8]
    float* __restrict__ out,            // [ntok*8 | ntok*2]
    int ntok)
{
    __shared__ float w_lds[16 * D];   // rows: e=0..7 route, e=8..15 noise
    __shared__ float bias[16];

    const int tid = threadIdx.x;

    const int wave = tid >> 6;
    const int lane = tid & 63;
    const int tg   = lane >> 3;       // token-group 0..7 (8 lanes each)
    const int c    = lane & 7;        // d-slice 0..7
    // group handles 2 tokens; wave covers 16; block covers 64
    const int tok0 = blockIdx.x * 64 + wave * 16 + tg * 2;

    // chunk q (0..11): lane c covers d = q*32 + c*4 .. +4
    const float* xr = x + (size_t)tok0 * D + c * 4;

    // ---- issue weight loads FIRST (oldest in vmem queue), then the first
    // x-superstep (stays in flight across the vmcnt the LDS writes need) ----
    float4 wr[3], wn[3];
    int widx[3];
#pragma unroll
    for (int r = 0; r < 3; ++r) {
        widx[r] = (tid + 256 * r) * 4;                    // < 3072
        wr[r] = *(const float4*)(w_route + widx[r]);
        wn[r] = *(const float4*)(w_noise + widx[r]);
    }

    float4 xa[2][3], xb[2][3];
#pragma unroll
    for (int qq = 0; qq < 3; ++qq) {
        xa[0][qq] = ntload4(xr + qq * 32);
        xa[1][qq] = ntload4(xr + D + qq * 32);
    }

#pragma unroll
    for (int r = 0; r < 3; ++r) {
        *(float4*)(w_lds + widx[r])        = wr[r];
        *(float4*)(w_lds + 3072 + widx[r]) = wn[r];
    }
    if (tid < 8)       bias[tid] = b_route[tid];
    else if (tid < 16) bias[tid] = b_noise[tid - 8];
    __syncthreads();

    float acc[2][16];
#pragma unroll
    for (int t = 0; t < 2; ++t)
#pragma unroll
        for (int e = 0; e < 16; ++e) acc[t][e] = 0.f;

#pragma unroll
    for (int s = 0; s < 4; ++s) {
        // prefetch next superstep (none at s=3: under nt a dummy re-read
        // would be real HBM traffic)
        if (s < 3) {
            const int qn = (s + 1) * 3;
#pragma unroll
            for (int qq = 0; qq < 3; ++qq) {
                xb[0][qq] = ntload4(xr + (qn + qq) * 32);
                xb[1][qq] = ntload4(xr + D + (qn + qq) * 32);
            }
        }
        // consume current superstep from registers
#pragma unroll
        for (int qq = 0; qq < 3; ++qq) {
            const int q = s * 3 + qq;
            const float* wj = w_lds + q * 32 + c * 4;
#pragma unroll
            for (int e = 0; e < 16; ++e) {
                float4 wv = *(const float4*)(wj + e * D);   // 8-way broadcast
                acc[0][e] += xa[0][qq].x * wv.x + xa[0][qq].y * wv.y
                           + xa[0][qq].z * wv.z + xa[0][qq].w * wv.w;
                acc[1][e] += xa[1][qq].x * wv.x + xa[1][qq].y * wv.y
                           + xa[1][qq].z * wv.z + xa[1][qq].w * wv.w;
            }
        }
        if (s < 3) {
#pragma unroll
            for (int qq = 0; qq < 3; ++qq) {
                xa[0][qq] = xb[0][qq];
                xa[1][qq] = xb[1][qq];
            }
        }
    }

    // partitioned reduction over the 8 d-slices:
    // xor1: keep the token matching bit0 of c (DPP, VALU pipe)
    // xor2 (DPP) + xor4 (ds_swizzle): plain reduce of the 16 sums.
    const bool b0 = (c & 1);
    float a1[16];
#pragma unroll
    for (int e = 0; e < 16; ++e) {
        float s = b0 ? acc[0][e] : acc[1][e];   // send the token we don't keep
        float k = b0 ? acc[1][e] : acc[0][e];   // keep token tok0 + (c&1)
        a1[e] = k + dpp_xor1(s);
    }
#pragma unroll
    for (int e = 0; e < 16; ++e) a1[e] += dpp_xor2(a1[e]);
#pragma unroll
    for (int e = 0; e < 16; ++e) a1[e] += swz_xor4(a1[e]);
    // lanes c<2 hold full sums for token tok0 + c

    if (c < 2) {
        const int token = tok0 + c;
        float4 n0 = ntload4(noise + (size_t)token * 8);
        float4 n1 = ntload4(noise + (size_t)token * 8 + 4);
        float nz[8] = {n0.x, n0.y, n0.z, n0.w, n1.x, n1.y, n1.z, n1.w};

        float noisy[8];
#pragma unroll
        for (int e = 0; e < 8; ++e) {
            float lg = a1[e] + bias[e];
            float nl = a1[8 + e] + bias[8 + e];
            // stable softplus: max(z,0) + log1p(exp(-|z|))
            float sp = fmaxf(nl, 0.f) + log1pf(expf(-fabsf(nl)));
            noisy[e] = lg + nz[e] * sp;
        }

        // top-2, jax.lax.top_k tie-break: earliest index wins ties
        float v0 = noisy[0]; int i0 = 0;
#pragma unroll
        for (int e = 1; e < 8; ++e)
            if (noisy[e] > v0) { v0 = noisy[e]; i0 = e; }
        float v1 = -INFINITY; int i1 = 0;
#pragma unroll
        for (int e = 0; e < 8; ++e)
            if (e != i0 && noisy[e] > v1) { v1 = noisy[e]; i1 = e; }

        // 2-way softmax (other experts exactly 0)
        float ex  = expf(v1 - v0);       // v1 <= v0
        float inv = 1.f / (1.f + ex);
        float p0  = inv;
        float p1  = ex * inv;

        float pr[8];
#pragma unroll
        for (int e = 0; e < 8; ++e)
            pr[e] = (e == i0) ? p0 : ((e == i1) ? p1 : 0.f);

        float* orow = out + (size_t)token * 8;
        ntstore4(orow,     make_float4(pr[0], pr[1], pr[2], pr[3]));
        ntstore4(orow + 4, make_float4(pr[4], pr[5], pr[6], pr[7]));

        ntstore2(out + (size_t)ntok * 8 + (size_t)token * 2,
                 make_float2((float)i0, (float)i1));
    }
}

extern "C" void kernel_launch(void* const* d_in, const int* in_sizes, int n_in,
                              void* d_out, int out_size, void* d_ws, size_t ws_size,
                              hipStream_t stream) {
    const float* x       = (const float*)d_in[0];
    const float* noise   = (const float*)d_in[1];
    const float* w_route = (const float*)d_in[2];
    const float* b_route = (const float*)d_in[3];
    const float* w_noise = (const float*)d_in[4];
    const float* b_noise = (const float*)d_in[5];
    float* out = (float*)d_out;

    const int ntok   = in_sizes[0] / D;   // 65536
    const int blocks = ntok / 64;         // 64 tokens per 256-thread block

    hipLaunchKernelGGL(noisy_topk_router_f32, dim3(blocks), dim3(256), 0, stream,
                       x, noise, w_route, b_route, w_noise, b_noise, out, ntok);
}

// Round 2
// 162.426 us; speedup vs baseline: 1.0337x; 1.0337x over previous
//
#include <hip/hip_runtime.h>
#include <math.h>

// NoisyTopkRouter, all-f32.
// x[ntok,384] @ {w_route,w_noise}[8,384]^T -> 16 logits/token,
// noisy = logit + noise*softplus(noise_logit), top-2 of 8, sparse softmax.
// Output: [ntok*8 probs f32 | ntok*2 indices-as-f32].
//
// R8 (final): revert of R7's non-temporal experiment (null-to-negative,
// 167.9 vs 164.4). Conclusion after three nulls (R2 LDS-halving, R6
// 6-deep prefetch, R7 nt-bypass): the timed region is a composite HBM
// roofline. Two 384MiB poison fills (~60us each, themselves HBM-bound at
// ~6.6 TB/s) precede the kernel; fill #2 leaves ~256MiB dirty in L3 whose
// writeback drains DURING our kernel (~40us of mandatory HBM writes).
// Our 100MB x-read interleaves with that drain -> kernel ~46us is the
// drain floor, not a kernel inefficiency. Region total: ~908MB HBM
// traffic in ~164us = 5.5 TB/s = ~87% of achievable 6.3 TB/s.

constexpr int D = 384;

__device__ __forceinline__ float dpp_xor1(float v) {   // lane ^ 1, quad_perm [1,0,3,2]
    return __int_as_float(__builtin_amdgcn_update_dpp(
        0, __float_as_int(v), 0xB1, 0xF, 0xF, true));
}
__device__ __forceinline__ float dpp_xor2(float v) {   // lane ^ 2, quad_perm [2,3,0,1]
    return __int_as_float(__builtin_amdgcn_update_dpp(
        0, __float_as_int(v), 0x4E, 0xF, 0xF, true));
}
__device__ __forceinline__ float swz_xor4(float v) {   // ds_swizzle BitMode xor 4
    return __int_as_float(__builtin_amdgcn_ds_swizzle(__float_as_int(v), 0x101F));
}

__global__ __launch_bounds__(256, 4) void noisy_topk_router_f32(
    const float* __restrict__ x,        // [ntok,384]
    const float* __restrict__ noise,    // [ntok,8]
    const float* __restrict__ w_route,  // [8,384]
    const float* __restrict__ b_route,  // [8]
    const float* __restrict__ w_noise,  // [8,384]
    const float* __restrict__ b_noise,  // [8]
    float* __restrict__ out,            // [ntok*8 | ntok*2]
    int ntok)
{
    __shared__ float w_lds[16 * D];   // rows: e=0..7 route, e=8..15 noise
    __shared__ float bias[16];

    const int tid = threadIdx.x;

    // stage weights: 2 x 3072 floats = 2 x 768 float4; 256 threads x 3 each
#pragma unroll
    for (int r = 0; r < 3; ++r) {
        int i = (tid + 256 * r) * 4;                       // < 3072
        *(float4*)(w_lds + i)        = *(const float4*)(w_route + i);
        *(float4*)(w_lds + 3072 + i) = *(const float4*)(w_noise + i);
    }
    if (tid < 8)       bias[tid] = b_route[tid];
    else if (tid < 16) bias[tid] = b_noise[tid - 8];
    __syncthreads();

    const int wave = tid >> 6;
    const int lane = tid & 63;
    const int tg   = lane >> 3;       // token-group 0..7 (8 lanes each)
    const int c    = lane & 7;        // d-slice 0..7
    // group handles 2 tokens; wave covers 16; block covers 64
    const int tok0 = blockIdx.x * 64 + wave * 16 + tg * 2;

    float acc[2][16];
#pragma unroll
    for (int t = 0; t < 2; ++t)
#pragma unroll
        for (int e = 0; e < 16; ++e) acc[t][e] = 0.f;

    // chunk q (0..11): lane c covers d = q*32 + c*4 .. +4
    const float* xr = x + (size_t)tok0 * D + c * 4;

    float4 xa[2][3], xb[2][3];
#pragma unroll
    for (int qq = 0; qq < 3; ++qq) {
        xa[0][qq] = *(const float4*)(xr + qq * 32);
        xa[1][qq] = *(const float4*)(xr + D + qq * 32);
    }

#pragma unroll
    for (int s = 0; s < 4; ++s) {
        // prefetch next superstep (s=3: dummy re-read of chunk 0..2)
        const int qn = (s < 3) ? (s + 1) * 3 : 0;
#pragma unroll
        for (int qq = 0; qq < 3; ++qq) {
            xb[0][qq] = *(const float4*)(xr + (qn + qq) * 32);
            xb[1][qq] = *(const float4*)(xr + D + (qn + qq) * 32);
        }
        // consume current superstep from registers
#pragma unroll
        for (int qq = 0; qq < 3; ++qq) {
            const int q = s * 3 + qq;
            const float* wj = w_lds + q * 32 + c * 4;
#pragma unroll
            for (int e = 0; e < 16; ++e) {
                float4 wv = *(const float4*)(wj + e * D);   // 8-way broadcast
                acc[0][e] += xa[0][qq].x * wv.x + xa[0][qq].y * wv.y
                           + xa[0][qq].z * wv.z + xa[0][qq].w * wv.w;
                acc[1][e] += xa[1][qq].x * wv.x + xa[1][qq].y * wv.y
                           + xa[1][qq].z * wv.z + xa[1][qq].w * wv.w;
            }
        }
#pragma unroll
        for (int qq = 0; qq < 3; ++qq) {
            xa[0][qq] = xb[0][qq];
            xa[1][qq] = xb[1][qq];
        }
    }

    // partitioned reduction over the 8 d-slices:
    // xor1: keep the token matching bit0 of c (DPP, VALU pipe)
    // xor2 (DPP) + xor4 (ds_swizzle): plain reduce of the 16 sums.
    const bool b0 = (c & 1);
    float a1[16];
#pragma unroll
    for (int e = 0; e < 16; ++e) {
        float s = b0 ? acc[0][e] : acc[1][e];   // send the token we don't keep
        float k = b0 ? acc[1][e] : acc[0][e];   // keep token tok0 + (c&1)
        a1[e] = k + dpp_xor1(s);
    }
#pragma unroll
    for (int e = 0; e < 16; ++e) a1[e] += dpp_xor2(a1[e]);
#pragma unroll
    for (int e = 0; e < 16; ++e) a1[e] += swz_xor4(a1[e]);
    // lanes c<2 hold full sums for token tok0 + c

    if (c < 2) {
        const int token = tok0 + c;
        float4 n0 = *(const float4*)(noise + (size_t)token * 8);
        float4 n1 = *(const float4*)(noise + (size_t)token * 8 + 4);
        float nz[8] = {n0.x, n0.y, n0.z, n0.w, n1.x, n1.y, n1.z, n1.w};

        float noisy[8];
#pragma unroll
        for (int e = 0; e < 8; ++e) {
            float lg = a1[e] + bias[e];
            float nl = a1[8 + e] + bias[8 + e];
            // stable softplus: max(z,0) + log1p(exp(-|z|))
            float sp = fmaxf(nl, 0.f) + log1pf(expf(-fabsf(nl)));
            noisy[e] = lg + nz[e] * sp;
        }

        // top-2, jax.lax.top_k tie-break: earliest index wins ties
        float v0 = noisy[0]; int i0 = 0;
#pragma unroll
        for (int e = 1; e < 8; ++e)
            if (noisy[e] > v0) { v0 = noisy[e]; i0 = e; }
        float v1 = -INFINITY; int i1 = 0;
#pragma unroll
        for (int e = 0; e < 8; ++e)
            if (e != i0 && noisy[e] > v1) { v1 = noisy[e]; i1 = e; }

        // 2-way softmax (other experts exactly 0)
        float ex  = expf(v1 - v0);       // v1 <= v0
        float inv = 1.f / (1.f + ex);
        float p0  = inv;
        float p1  = ex * inv;

        float pr[8];
#pragma unroll
        for (int e = 0; e < 8; ++e)
            pr[e] = (e == i0) ? p0 : ((e == i1) ? p1 : 0.f);

        float* orow = out + (size_t)token * 8;
        *(float4*)(orow)     = make_float4(pr[0], pr[1], pr[2], pr[3]);
        *(float4*)(orow + 4) = make_float4(pr[4], pr[5], pr[6], pr[7]);

        *(float2*)(out + (size_t)ntok * 8 + (size_t)token * 2) =
            make_float2((float)i0, (float)i1);
    }
}

extern "C" void kernel_launch(void* const* d_in, const int* in_sizes, int n_in,
                              void* d_out, int out_size, void* d_ws, size_t ws_size,
                              hipStream_t stream) {
    const float* x       = (const float*)d_in[0];
    const float* noise   = (const float*)d_in[1];
    const float* w_route = (const float*)d_in[2];
    const float* b_route = (const float*)d_in[3];
    const float* w_noise = (const float*)d_in[4];
    const float* b_noise = (const float*)d_in[5];
    float* out = (float*)d_out;

    const int ntok   = in_sizes[0] / D;   // 65536
    const int blocks = ntok / 64;         // 64 tokens per 256-thread block

    hipLaunchKernelGGL(noisy_topk_router_f32, dim3(blocks), dim3(256), 0, stream,
                       x, noise, w_route, b_route, w_noise, b_noise, out, ntok);
}